// Round 9
// baseline (457.192 us; speedup 1.0000x reference)
//
#include <hip/hip_runtime.h>

// SSIM loss, three-phase separable conv, ALL phases shaped like R4's
// proven 70%-busy loop (batched contiguous b128 LDS reads + long VALU
// tail; stage loop load->store only). 96 planes of 512x512.
// 64x16 tile, 640 threads, 24576 blocks.
//
// R12 post-mortem: 32% busy again, VGPR 28, bank conflicts 0.29M->12.3M.
// Root cause isolated by comparing against R4 (the only 70%-busy round):
// R12 phase 1 read a COLUMN of the stage (12 x b64, stride 608B,
// unbatchable, bank-aliased) with ~4 FMA per read, plus 592-unit/512-thr
// barrier convoys. R4 batches 6 contiguous b128 then runs a ~100-inst
// tail -> one wave self-hides LDS latency even at low VGPR count.
//
// R13 changes:
//  * stgT TRANSPOSED [74 cols][stride 30 rows] v2f: vertical conv reads
//    12 contiguous v2f = 6 batched b128 (R4's exact q0..q5 shape).
//    Stride 30 v2f = 240B -> quad step 15 (odd) -> 8-lane phase groups
//    hit 8 distinct bank-quads: conflict-free reads; writes ~2-way (free).
//  * 640 threads: P1's 592 units <= 640 -> ONE unit per thread, convoy
//    gone. P2: 512 threads x 2 px. P0: 1924 elems, ~3 iters each.
//  * P2 batches its 12 b128 h reads before the FMA sweep.
//  * LDS 37.4KB -> 3 blocks/CU x 10 waves = 30 waves/CU.
//  * No waves_per_eu attribute (R7: spills; R9: clamp; R10/11: squeeze).

typedef float v2f __attribute__((ext_vector_type(2)));
typedef float v4f __attribute__((ext_vector_type(4)));

#define IMG 512
#define TW 64               // tile width  (output cols)
#define TH 16               // tile height (output rows)
#define HALO 5
#define SROWS 26            // TH + 2*HALO staged rows
#define SCOLS 74            // TW + 2*HALO staged cols
#define STRIDE_T 30         // stgT row-dim stride in v2f units (even: 16B
                            // alignment for b128; 240B -> odd quad step)
#define HSTRIDE 75          // h stride in v4f units; odd -> conflict-free
#define VSEGS 8             // TH/2 pass-V segments (RPTV=2)
#define NTHR 640
#define NPIX 25165824.0     // 32*3*512*512

// Gaussian(sigma=1.5, 11 taps), normalized, fp32 (verified R1-R12)
__device__ constexpr float WT[11] = {
    0.00102838f, 0.00759876f, 0.03600077f, 0.10936068f, 0.21300552f,
    0.26601173f,
    0.21300552f, 0.10936068f, 0.03600077f, 0.00759876f, 0.00102838f};

__global__ __launch_bounds__(NTHR)
void ssim_main(const float* __restrict__ clean,
               const float* __restrict__ adv,
               double* __restrict__ accum)
{
    // stgT[col][row]: {s=x+y, d=x-y}, transposed for contiguous V-reads
    __shared__ __align__(16) v2f stgT[SCOLS * STRIDE_T];   // 17,760 B
    // h[row][col]: {convV(s), convV(d), convV(s^2), convV(d^2)}
    __shared__ __align__(16) v4f hbuf[TH * HSTRIDE];       // 19,200 B
    __shared__ float wpart[10];

    const int tid = threadIdx.x;
    const int b = blockIdx.x;
    const int plane = b >> 8;             // 256 tiles per plane
    const int t8 = b & 255;
    const int tile_x = (t8 & 7) * TW;     // 8 tiles across
    const int tile_y = (t8 >> 3) * TH;    // 32 tiles down; (x,y)&(x,y+1)
                                          // are 8 blocks apart = same XCD

    const float* __restrict__ cp = clean + (size_t)plane * (IMG * IMG);
    const float* __restrict__ ap = adv   + (size_t)plane * (IMG * IMG);

    // ---- Phase 0: stage {s,d} global -> LDS transposed ----
    // Read row-major (coalesced), write stgT[c][r] (stride 240B, ~2-way
    // bank aliasing = free). Load->store only: iterations independent,
    // loads pipeline even at low VGPR (R4-proven).
    for (int idx = tid; idx < SROWS * SCOLS; idx += NTHR) {
        const int r = idx / SCOLS;
        const int c = idx - r * SCOLS;
        const int gr = tile_y + r - HALO;
        const int gc = tile_x + c - HALO;
        v2f v = {0.f, 0.f};
        if ((unsigned)gr < IMG && (unsigned)gc < IMG) {
            const int gi = gr * IMG + gc;
            const float x = cp[gi];
            const float y = ap[gi];
            v = (v2f){x + y, x - y};
        }
        stgT[c * STRIDE_T + r] = v;
    }
    __syncthreads();

    // ---- Phase 1: vertical conv, stgT -> h (one unit per thread) ----
    // unit = (col uc, seg): h rows or0, or0+1 from stage rows or0..or0+11,
    // read as 6 contiguous b128 (R4's exact batched shape).
    if (tid < SCOLS * VSEGS) {            // 592 units
        const int seg = tid / SCOLS;      // 0..7
        const int uc  = tid - seg * SCOLS;
        const int or0 = seg * 2;          // first h row (even -> aligned)

        const v4f* __restrict__ sp =
            (const v4f*)&stgT[uc * STRIDE_T + or0];
        const v4f q0 = sp[0], q1 = sp[1], q2 = sp[2],
                  q3 = sp[3], q4 = sp[4], q5 = sp[5];
        v2f t[12];
        t[0]  = (v2f){q0.x, q0.y}; t[1]  = (v2f){q0.z, q0.w};
        t[2]  = (v2f){q1.x, q1.y}; t[3]  = (v2f){q1.z, q1.w};
        t[4]  = (v2f){q2.x, q2.y}; t[5]  = (v2f){q2.z, q2.w};
        t[6]  = (v2f){q3.x, q3.y}; t[7]  = (v2f){q3.z, q3.w};
        t[8]  = (v2f){q4.x, q4.y}; t[9]  = (v2f){q4.z, q4.w};
        t[10] = (v2f){q5.x, q5.y}; t[11] = (v2f){q5.z, q5.w};

        v2f aA0 = {0.f, 0.f}, aA1 = {0.f, 0.f};
        v2f aB0 = {0.f, 0.f}, aB1 = {0.f, 0.f};
        #pragma unroll
        for (int j = 0; j < 12; ++j) {
            const v2f tv = t[j];
            const v2f pp = tv * tv;       // {s^2, d^2}
            if (j < 11) {
                const float w = WT[j];
                aA0 += w * tv; aB0 += w * pp;
            }
            if (j > 0) {
                const float w = WT[j - 1];
                aA1 += w * tv; aB1 += w * pp;
            }
        }
        hbuf[or0 * HSTRIDE + uc]       = (v4f){aA0.x, aA0.y, aB0.x, aB0.y};
        hbuf[(or0 + 1) * HSTRIDE + uc] = (v4f){aA1.x, aA1.y, aB1.x, aB1.y};
    }
    __syncthreads();

    // ---- Phase 2: horizontal conv, h -> regs, + SSIM (2 px/thread) ----
    // thread: row = tid&15, col-seg cs = tid>>4 (cols 2cs, 2cs+1).
    // 12 contiguous b128 batched; quad (3*row+2*cs+k)%8: lanes 0..7 =
    // rows 0..7 -> {0,3,6,1,4,7,2,5} all 8 quads -> conflict-free.
    const float C1 = 1e-4f;   // 0.01^2
    const float C2 = 9e-4f;   // 0.03^2
    float lsum = 0.f;
    if (tid < 512) {
        const int row = tid & 15;
        const int cs  = tid >> 4;             // 0..31
        const int c0  = cs * 2;
        const v4f* __restrict__ hrow = hbuf + row * HSTRIDE + c0;

        v4f h[12];
        #pragma unroll
        for (int k = 0; k < 12; ++k) h[k] = hrow[k];   // batched reads

        v2f A0 = {0.f, 0.f}, A1 = {0.f, 0.f};
        v2f B0 = {0.f, 0.f}, B1 = {0.f, 0.f};
        #pragma unroll
        for (int k = 0; k < 12; ++k) {
            const v2f hA = {h[k].x, h[k].y};
            const v2f hB = {h[k].z, h[k].w};
            if (k < 11) {
                const float w = WT[k];
                A0 += w * hA; B0 += w * hB;
            }
            if (k > 0) {
                const float w = WT[k - 1];
                A1 += w * hA; B1 += w * hB;
            }
        }

        // u=conv2(s), v=conv2(d), P=conv2(s^2), Q=conv2(d^2), U=u^2, V=v^2:
        //   2*mu12        = (U-V)/2        mu1^2+mu2^2  = (U+V)/2
        //   2*sigma12     = (P-Q)/2-(U-V)/2
        //   sig1^2+sig2^2 = (P+Q)/2-(U+V)/2
        #pragma unroll
        for (int o = 0; o < 2; ++o) {
            const v2f a  = o ? A1 : A0;
            const v2f bb = o ? B1 : B0;
            const float U = a.x * a.x;
            const float V = a.y * a.y;
            const float halfUmV = 0.5f * (U - V);
            const float halfUpV = 0.5f * (U + V);
            const float num1 = halfUmV + C1;
            const float num2 = 0.5f * (bb.x - bb.y) - halfUmV + C2;
            const float den1 = halfUpV + C1;
            const float den2 = 0.5f * (bb.x + bb.y) - halfUpV + C2;
            lsum += (num1 * num2) * __builtin_amdgcn_rcpf(den1 * den2);
        }
    }

    // ---- Reduce: wave shuffle -> LDS -> one atomic per block ----
    #pragma unroll
    for (int off = 32; off > 0; off >>= 1)
        lsum += __shfl_down(lsum, off);
    const int lane = tid & 63;
    const int wave = tid >> 6;                // 0..9
    if (lane == 0) wpart[wave] = lsum;
    __syncthreads();
    if (tid == 0) {
        float bs = 0.f;
        #pragma unroll
        for (int w = 0; w < 10; ++w) bs += wpart[w];
        atomicAdd(accum, (double)bs);
    }
}

__global__ void ssim_finalize(const double* __restrict__ accum,
                              float* __restrict__ out)
{
    if (threadIdx.x == 0) {
        out[0] = 1.f - (float)(accum[0] / NPIX);
    }
}

extern "C" void kernel_launch(void* const* d_in, const int* in_sizes, int n_in,
                              void* d_out, int out_size, void* d_ws, size_t ws_size,
                              hipStream_t stream)
{
    const float* clean = (const float*)d_in[0];
    const float* adv   = (const float*)d_in[1];
    float* out = (float*)d_out;
    double* accum = (double*)d_ws;

    hipMemsetAsync(accum, 0, sizeof(double), stream);

    const int nblocks = 96 * 256;  // 96 planes * (8x32 tiles of 64x16)
    ssim_main<<<nblocks, NTHR, 0, stream>>>(clean, adv, accum);
    ssim_finalize<<<1, 64, 0, stream>>>(accum, out);
}